// Round 1
// baseline (237.208 us; speedup 1.0000x reference)
//
#include <hip/hip_runtime.h>
#include <hip/hip_bf16.h>

#define B_DIM 8192
#define IN_DIM 2048
#define OUT_DIM 2048
#define K2 (2 * IN_DIM)  // hi|lo concatenated K

typedef __attribute__((ext_vector_type(8))) __bf16 bf16x8;
typedef __attribute__((ext_vector_type(4))) float f32x4;

__device__ __forceinline__ unsigned short f32_to_bf16_rne(float f) {
    unsigned u = __float_as_uint(f);
    unsigned r = (u + 0x7FFFu + ((u >> 16) & 1u)) >> 16;
    return (unsigned short)r;
}
__device__ __forceinline__ float bf16u_to_f32(unsigned short h) {
    return __uint_as_float(((unsigned)h) << 16);
}

__device__ __forceinline__ void gload16(const void* g, void* l) {
    __builtin_amdgcn_global_load_lds(
        (const __attribute__((address_space(1))) void*)g,
        (__attribute__((address_space(3))) void*)l,
        16, 0, 0);
}

// ---------------- Stage 1: per-column partial sums (deterministic) -------------
__global__ void k_stats(const float* __restrict__ x, float* __restrict__ psum,
                        float* __restrict__ psq) {
    int col = blockIdx.x * 256 + threadIdx.x;     // 8 col-blocks
    int chunk = blockIdx.y;                       // 32 row-chunks of 256 rows
    const float* p = x + (size_t)chunk * 256 * IN_DIM + col;
    float s = 0.f, s2 = 0.f;
#pragma unroll 8
    for (int r = 0; r < 256; ++r) {
        float v = p[(size_t)r * IN_DIM];
        s += v;
        s2 = fmaf(v, v, s2);
    }
    psum[chunk * IN_DIM + col] = s;
    psq[chunk * IN_DIM + col] = s2;
}

// ---------------- Stage 2: finalize mean/var -> scale/shift --------------------
__global__ void k_finalize(const float* __restrict__ psum, const float* __restrict__ psq,
                           const float* __restrict__ gamma, const float* __restrict__ beta,
                           float* __restrict__ scale, float* __restrict__ shift) {
    int c = blockIdx.x * 256 + threadIdx.x;
    float s = 0.f, s2 = 0.f;
#pragma unroll
    for (int ch = 0; ch < 32; ++ch) {
        s += psum[ch * IN_DIM + c];
        s2 += psq[ch * IN_DIM + c];
    }
    float mean = s * (1.0f / B_DIM);
    float var = fmaf(-mean, mean, s2 * (1.0f / B_DIM));
    float sc = gamma[c] * rsqrtf(var + 1e-5f);
    scale[c] = sc;
    shift[c] = fmaf(-mean, sc, beta[c]);
}

// ---------------- Stage 3: xn -> bf16 hi|lo concatenated A [8192][4096] --------
__global__ void k_prep_a(const float* __restrict__ x, const float* __restrict__ scale,
                         const float* __restrict__ shift, unsigned short* __restrict__ Acat) {
    int row = blockIdx.x;
    int c0 = threadIdx.x * 8;
    const float4* px = (const float4*)(x + (size_t)row * IN_DIM + c0);
    float4 v0 = px[0], v1 = px[1];
    const float4* ps = (const float4*)(scale + c0);
    float4 s0 = ps[0], s1 = ps[1];
    const float4* pb = (const float4*)(shift + c0);
    float4 b0 = pb[0], b1 = pb[1];
    float xs[8] = {v0.x, v0.y, v0.z, v0.w, v1.x, v1.y, v1.z, v1.w};
    float ss[8] = {s0.x, s0.y, s0.z, s0.w, s1.x, s1.y, s1.z, s1.w};
    float bb[8] = {b0.x, b0.y, b0.z, b0.w, b1.x, b1.y, b1.z, b1.w};
    union { unsigned short u[8]; uint4 v; } hi, lo;
#pragma unroll
    for (int j = 0; j < 8; ++j) {
        float xn = fmaf(xs[j], ss[j], bb[j]);
        unsigned short h = f32_to_bf16_rne(xn);
        float r = xn - bf16u_to_f32(h);
        hi.u[j] = h;
        lo.u[j] = f32_to_bf16_rne(r);
    }
    size_t base = (size_t)row * K2;
    *(uint4*)(Acat + base + c0) = hi.v;
    *(uint4*)(Acat + base + IN_DIM + c0) = lo.v;
}

// ---------------- Stage 4: weight sign -> bf16 +-1 [2048][2048] ----------------
__global__ void k_prep_b(const float* __restrict__ w, unsigned short* __restrict__ Bsgn) {
    int row = blockIdx.x;
    int c0 = threadIdx.x * 8;
    const float4* pw = (const float4*)(w + (size_t)row * IN_DIM + c0);
    float4 v0 = pw[0], v1 = pw[1];
    float wv[8] = {v0.x, v0.y, v0.z, v0.w, v1.x, v1.y, v1.z, v1.w};
    union { unsigned short u[8]; uint4 v; } sb;
#pragma unroll
    for (int j = 0; j < 8; ++j) sb.u[j] = (wv[j] >= 0.0f) ? 0x3F80u : 0xBF80u;
    *(uint4*)(Bsgn + (size_t)row * IN_DIM + c0) = sb.v;
}

// ---------------- Stage 5: GEMM  y = A_cat (M x K2) * Bsgn^T, hardtanh ---------
#define BM 128
#define BN 128
#define BK 32
#define NWG ((B_DIM / BM) * (OUT_DIM / BN))  // 64*16 = 1024

__global__ __launch_bounds__(256) void k_gemm(const unsigned short* __restrict__ A,
                                              const unsigned short* __restrict__ Bsgn,
                                              float* __restrict__ out) {
    __shared__ unsigned short As[BM * BK];  // [128][32]
    __shared__ unsigned short Bs[BN * BK];  // [128][32]

    // XCD-aware swizzle (1024 % 8 == 0 -> bijective)
    int bid = blockIdx.x;
    int swz = (bid & 7) * (NWG / 8) + (bid >> 3);
    int mt = swz >> 4;   // 64 m-tiles
    int nt = swz & 15;   // 16 n-tiles
    int m0 = mt * BM, n0 = nt * BN;

    int t = threadIdx.x;
    int lane = t & 63, wave = t >> 6;
    int wr = (wave >> 1) * 64;       // wave row base in tile
    int wc = (wave & 1) * 64;        // wave col base in tile
    int lrow = lane & 15;
    int kcol = (lane >> 4) * 8;

    // staging coords: thread t covers 16B at flat byte offset t*16 (+4KB per load)
    int srow = t >> 2;           // 0..63
    int scol = (t & 3) * 8;      // element col in [0,32)
    const unsigned short* aBase = A + (size_t)(m0 + srow) * K2 + scol;
    const unsigned short* bBase = Bsgn + (size_t)(n0 + srow) * IN_DIM + scol;
    unsigned short* asDst = &As[srow * BK + scol];
    unsigned short* bsDst = &Bs[srow * BK + scol];

    f32x4 acc[4][4] = {};

    for (int kt = 0; kt < K2 / BK; ++kt) {
        int k0 = kt * BK;
        int bk0 = k0 & (IN_DIM - 1);   // sign matrix repeats for lo half
        gload16(aBase + k0, asDst);
        gload16(aBase + (size_t)64 * K2 + k0, asDst + 64 * BK);
        gload16(bBase + bk0, bsDst);
        gload16(bBase + (size_t)64 * IN_DIM + bk0, bsDst + 64 * BK);
        __syncthreads();   // compiler drains vmcnt before barrier -> LDS ready

        bf16x8 a[4], b[4];
#pragma unroll
        for (int m = 0; m < 4; ++m)
            a[m] = *(const bf16x8*)&As[(wr + m * 16 + lrow) * BK + kcol];
#pragma unroll
        for (int n = 0; n < 4; ++n)
            b[n] = *(const bf16x8*)&Bs[(wc + n * 16 + lrow) * BK + kcol];
#pragma unroll
        for (int m = 0; m < 4; ++m)
#pragma unroll
            for (int n = 0; n < 4; ++n)
                acc[m][n] = __builtin_amdgcn_mfma_f32_16x16x32_bf16(a[m], b[n], acc[m][n], 0, 0, 0);
        __syncthreads();   // protect LDS from next iteration's staging
    }

    // epilogue: C/D map col=lane&15, row=(lane>>4)*4+reg; fused hardtanh
#pragma unroll
    for (int m = 0; m < 4; ++m) {
#pragma unroll
        for (int n = 0; n < 4; ++n) {
#pragma unroll
            for (int r = 0; r < 4; ++r) {
                int row = m0 + wr + m * 16 + (lane >> 4) * 4 + r;
                int col = n0 + wc + n * 16 + (lane & 15);
                float v = acc[m][n][r];
                v = fminf(fmaxf(v, -1.0f), 1.0f);
                out[(size_t)row * OUT_DIM + col] = v;
            }
        }
    }
}

extern "C" void kernel_launch(void* const* d_in, const int* in_sizes, int n_in,
                              void* d_out, int out_size, void* d_ws, size_t ws_size,
                              hipStream_t stream) {
    const float* x = (const float*)d_in[0];
    const float* w = (const float*)d_in[1];
    const float* gamma = (const float*)d_in[2];
    const float* beta = (const float*)d_in[3];
    float* out = (float*)d_out;

    float* wsf = (float*)d_ws;
    float* psum = wsf;                                  // 32*2048 f32
    float* psq = wsf + 32 * IN_DIM;                     // 32*2048 f32
    float* scale = wsf + 64 * IN_DIM;                   // 2048 f32
    float* shift = wsf + 65 * IN_DIM;                   // 2048 f32
    unsigned short* Bsgn = (unsigned short*)(wsf + 66 * IN_DIM);      // 8 MB
    unsigned short* Acat = Bsgn + (size_t)OUT_DIM * IN_DIM;           // 64 MB

    k_stats<<<dim3(8, 32), 256, 0, stream>>>(x, psum, psq);
    k_finalize<<<8, 256, 0, stream>>>(psum, psq, gamma, beta, scale, shift);
    k_prep_a<<<B_DIM, 256, 0, stream>>>(x, scale, shift, Acat);
    k_prep_b<<<OUT_DIM, 256, 0, stream>>>(w, Bsgn);
    k_gemm<<<NWG, 256, 0, stream>>>(Acat, Bsgn, out);
}

// Round 2
// 169.055 us; speedup vs baseline: 1.4031x; 1.4031x over previous
//
#include <hip/hip_runtime.h>
#include <hip/hip_bf16.h>

#define B_DIM 8192
#define IN_DIM 2048
#define OUT_DIM 2048
#define K2 (2 * IN_DIM)  // hi|lo concatenated K = 4096

typedef __attribute__((ext_vector_type(8))) __bf16 bf16x8;
typedef __attribute__((ext_vector_type(4))) float f32x4;

__device__ __forceinline__ unsigned short f32_to_bf16_rne(float f) {
    unsigned u = __float_as_uint(f);
    unsigned r = (u + 0x7FFFu + ((u >> 16) & 1u)) >> 16;
    return (unsigned short)r;
}
__device__ __forceinline__ float bf16u_to_f32(unsigned short h) {
    return __uint_as_float(((unsigned)h) << 16);
}

__device__ __forceinline__ void gload16(const void* g, void* l) {
    __builtin_amdgcn_global_load_lds(
        (const __attribute__((address_space(1))) void*)g,
        (__attribute__((address_space(3))) void*)l,
        16, 0, 0);
}

// ---------------- Stage 1: per-column partial sums (deterministic) -------------
__global__ void k_stats(const float* __restrict__ x, float* __restrict__ psum,
                        float* __restrict__ psq) {
    int col = blockIdx.x * 256 + threadIdx.x;
    int chunk = blockIdx.y;
    const float* p = x + (size_t)chunk * 256 * IN_DIM + col;
    float s = 0.f, s2 = 0.f;
#pragma unroll 8
    for (int r = 0; r < 256; ++r) {
        float v = p[(size_t)r * IN_DIM];
        s += v;
        s2 = fmaf(v, v, s2);
    }
    psum[chunk * IN_DIM + col] = s;
    psq[chunk * IN_DIM + col] = s2;
}

// ---------------- Stage 2: finalize mean/var -> scale/shift --------------------
__global__ void k_finalize(const float* __restrict__ psum, const float* __restrict__ psq,
                           const float* __restrict__ gamma, const float* __restrict__ beta,
                           float* __restrict__ scale, float* __restrict__ shift) {
    int c = blockIdx.x * 256 + threadIdx.x;
    float s = 0.f, s2 = 0.f;
#pragma unroll
    for (int ch = 0; ch < 32; ++ch) {
        s += psum[ch * IN_DIM + c];
        s2 += psq[ch * IN_DIM + c];
    }
    float mean = s * (1.0f / B_DIM);
    float var = fmaf(-mean, mean, s2 * (1.0f / B_DIM));
    float sc = gamma[c] * rsqrtf(var + 1e-5f);
    scale[c] = sc;
    shift[c] = fmaf(-mean, sc, beta[c]);
}

// ---------------- Stage 3: xn -> bf16 hi|lo concatenated A [8192][4096] --------
__global__ void k_prep_a(const float* __restrict__ x, const float* __restrict__ scale,
                         const float* __restrict__ shift, unsigned short* __restrict__ Acat) {
    int row = blockIdx.x;
    int c0 = threadIdx.x * 8;
    const float4* px = (const float4*)(x + (size_t)row * IN_DIM + c0);
    float4 v0 = px[0], v1 = px[1];
    const float4* ps = (const float4*)(scale + c0);
    float4 s0 = ps[0], s1 = ps[1];
    const float4* pb = (const float4*)(shift + c0);
    float4 b0 = pb[0], b1 = pb[1];
    float xs[8] = {v0.x, v0.y, v0.z, v0.w, v1.x, v1.y, v1.z, v1.w};
    float ss[8] = {s0.x, s0.y, s0.z, s0.w, s1.x, s1.y, s1.z, s1.w};
    float bb[8] = {b0.x, b0.y, b0.z, b0.w, b1.x, b1.y, b1.z, b1.w};
    union { unsigned short u[8]; uint4 v; } hi, lo;
#pragma unroll
    for (int j = 0; j < 8; ++j) {
        float xn = fmaf(xs[j], ss[j], bb[j]);
        unsigned short h = f32_to_bf16_rne(xn);
        float r = xn - bf16u_to_f32(h);
        hi.u[j] = h;
        lo.u[j] = f32_to_bf16_rne(r);
    }
    size_t base = (size_t)row * K2;
    *(uint4*)(Acat + base + c0) = hi.v;
    *(uint4*)(Acat + base + IN_DIM + c0) = lo.v;
}

// ---------------- Stage 4: weight sign -> bf16 +-1 [2048][2048] ----------------
__global__ void k_prep_b(const float* __restrict__ w, unsigned short* __restrict__ Bsgn) {
    int row = blockIdx.x;
    int c0 = threadIdx.x * 8;
    const float4* pw = (const float4*)(w + (size_t)row * IN_DIM + c0);
    float4 v0 = pw[0], v1 = pw[1];
    float wv[8] = {v0.x, v0.y, v0.z, v0.w, v1.x, v1.y, v1.z, v1.w};
    union { unsigned short u[8]; uint4 v; } sb;
#pragma unroll
    for (int j = 0; j < 8; ++j) sb.u[j] = (wv[j] >= 0.0f) ? 0x3F80u : 0xBF80u;
    *(uint4*)(Bsgn + (size_t)row * IN_DIM + c0) = sb.v;
}

// ---------------- Stage 5: 256x256-tile 8-wave 4-phase MFMA GEMM ---------------
// y = Acat (8192 x 4096) * Bsgn^T (sign matrix repeats over the two K halves),
// hardtanh fused. T1 XCD swizzle + T2 LDS xor-swizzle + T3/T4 counted vmcnt +
// T5 setprio.
#define BM 256
#define BN 256
#define BK 64
#define MT (B_DIM / BM)    // 32
#define NT (OUT_DIM / BN)  // 8
#define NWG (MT * NT)      // 256
#define NKT (K2 / BK)      // 64
#define TILE_E (BM * BK)   // 16384 elems = 32 KB

#define MEMF() asm volatile("" ::: "memory")
#define BARRIER() do { MEMF(); __builtin_amdgcn_s_barrier(); MEMF(); } while (0)
#define WAITVM(N) asm volatile("s_waitcnt vmcnt(" #N ")" ::: "memory")

__global__ __launch_bounds__(512, 2) void k_gemm(const unsigned short* __restrict__ A,
                                                 const unsigned short* __restrict__ Bsgn,
                                                 float* __restrict__ out) {
    __shared__ __align__(16) unsigned short sh[4 * TILE_E];  // [buf][A,B] = 128 KiB

    // T1: XCD-aware swizzle (256 % 8 == 0 -> bijective)
    int bid = blockIdx.x;
    int swz = (bid & 7) * (NWG / 8) + (bid >> 3);
    int mt = swz >> 3, nt = swz & 7;
    int m0 = mt * BM, n0 = nt * BN;

    int t = threadIdx.x;
    int lane = t & 63, w = t >> 6;
    int wm = w >> 2, wn = w & 3;       // 2 x 4 wave grid; per-wave out = 128 x 64
    int lrow = lane & 15, lg = lane >> 4, lx = lane & 7;

    // T2 read-side swizzle: slot(16B) ^= row&7; row&7 == lane&7 for all frags
    int s0 = ((lg ^ lx) << 3);         // ks=0: logical slot lg
    int s1 = (((lg + 4) ^ lx) << 3);   // ks=1: logical slot lg+4
    int aRdBase = (wm * 128 + lrow) * BK;
    int bRdBase = (wn * 64 + lrow) * BK;

    // staging: thread t covers row trow of each 64-row chunk; source slot is
    // pre-swizzled so linear LDS dest + swizzled read = identity (rule 21)
    int trow = t >> 3;
    int tslot = (t & 7) ^ (trow & 7);

    auto stageA = [&](unsigned short* dst, int crow, int kt) {
        const unsigned short* src =
            A + (size_t)(m0 + crow + trow) * K2 + kt * BK + (tslot << 3);
        gload16(src, dst + crow * BK + t * 8);
    };
    auto stageB = [&](unsigned short* dst, int crow, int kt) {
        const unsigned short* src =
            Bsgn + (size_t)(n0 + crow + trow) * IN_DIM + ((kt * BK) & (IN_DIM - 1)) + (tslot << 3);
        gload16(src, dst + crow * BK + t * 8);
    };

    f32x4 acc[8][4] = {};

    // Prologue: stage tile 0 in steady-state issue order; leave last 2 in flight
    {
        unsigned short* A0 = sh;
        unsigned short* B0 = sh + TILE_E;
        stageA(A0, 0, 0);
        stageA(A0, 128, 0);
        stageB(B0, 0, 0);
        stageB(B0, 64, 0);
        stageB(B0, 128, 0);
        stageB(B0, 192, 0);
        stageA(A0, 64, 0);
        stageA(A0, 192, 0);
        WAITVM(2);
        BARRIER();
    }

    for (int T = 0; T < NKT; ++T) {
        int cur = T & 1, nxt = cur ^ 1;
        const unsigned short* Ab = sh + (cur * 2 + 0) * TILE_E;
        const unsigned short* Bb = sh + (cur * 2 + 1) * TILE_E;
        unsigned short* An = sh + (nxt * 2 + 0) * TILE_E;
        unsigned short* Bn = sh + (nxt * 2 + 1) * TILE_E;
        bool pf = (T < NKT - 1);

        // B fragments for the whole tile (persist in regs across phases)
        bf16x8 bf[4][2];
#pragma unroll
        for (int n = 0; n < 4; ++n) {
            bf[n][0] = *(const bf16x8*)&Bb[bRdBase + n * (16 * BK) + s0];
            bf[n][1] = *(const bf16x8*)&Bb[bRdBase + n * (16 * BK) + s1];
        }

#pragma unroll
        for (int p = 0; p < 4; ++p) {
            // A fragments for this phase's m-quadrant
            bf16x8 af[2][2];
#pragma unroll
            for (int mi = 0; mi < 2; ++mi) {
                af[mi][0] = *(const bf16x8*)&Ab[aRdBase + (2 * p + mi) * (16 * BK) + s0];
                af[mi][1] = *(const bf16x8*)&Ab[aRdBase + (2 * p + mi) * (16 * BK) + s1];
            }
            // stage next tile, dependency-ordered: early-needed chunks first
            if (pf) {
                if (p == 0) { stageA(An, 0, T + 1); stageA(An, 128, T + 1); }
                else if (p == 1) { stageB(Bn, 0, T + 1); stageB(Bn, 64, T + 1); }
                else if (p == 2) { stageB(Bn, 128, T + 1); stageB(Bn, 192, T + 1); }
                else { stageA(An, 64, T + 1); stageA(An, 192, T + 1); }
            }
            BARRIER();
            __builtin_amdgcn_s_setprio(1);
#pragma unroll
            for (int mi = 0; mi < 2; ++mi)
#pragma unroll
                for (int n = 0; n < 4; ++n)
#pragma unroll
                    for (int ks = 0; ks < 2; ++ks)
                        acc[2 * p + mi][n] = __builtin_amdgcn_mfma_f32_16x16x32_bf16(
                            af[mi][ks], bf[n][ks], acc[2 * p + mi][n], 0, 0, 0);
            __builtin_amdgcn_s_setprio(0);
            // T4: counted waits, never 0 in steady state
            if (p == 1) {
                if (pf) { WAITVM(4); } else { WAITVM(0); }
            }
            if (p == 3 && pf) { WAITVM(2); }
            BARRIER();
        }
    }

    // Epilogue: C/D map col=lane&15, row=(lane>>4)*4+reg; fused hardtanh
#pragma unroll
    for (int m = 0; m < 8; ++m) {
#pragma unroll
        for (int n = 0; n < 4; ++n) {
#pragma unroll
            for (int r = 0; r < 4; ++r) {
                int row = m0 + wm * 128 + m * 16 + lg * 4 + r;
                int col = n0 + wn * 64 + n * 16 + lrow;
                float v = acc[m][n][r];
                v = fminf(fmaxf(v, -1.0f), 1.0f);
                out[(size_t)row * OUT_DIM + col] = v;
            }
        }
    }
}

extern "C" void kernel_launch(void* const* d_in, const int* in_sizes, int n_in,
                              void* d_out, int out_size, void* d_ws, size_t ws_size,
                              hipStream_t stream) {
    const float* x = (const float*)d_in[0];
    const float* w = (const float*)d_in[1];
    const float* gamma = (const float*)d_in[2];
    const float* beta = (const float*)d_in[3];
    float* out = (float*)d_out;

    float* wsf = (float*)d_ws;
    float* psum = wsf;                                   // 32*2048 f32
    float* psq = wsf + 32 * IN_DIM;                      // 32*2048 f32
    float* scale = wsf + 64 * IN_DIM;                    // 2048 f32
    float* shift = wsf + 65 * IN_DIM;                    // 2048 f32
    unsigned short* Bsgn = (unsigned short*)(wsf + 66 * IN_DIM);  // 8 MB
    unsigned short* Acat = Bsgn + (size_t)OUT_DIM * IN_DIM;       // 64 MB

    k_stats<<<dim3(8, 32), 256, 0, stream>>>(x, psum, psq);
    k_finalize<<<8, 256, 0, stream>>>(psum, psq, gamma, beta, scale, shift);
    k_prep_a<<<B_DIM, 256, 0, stream>>>(x, scale, shift, Acat);
    k_prep_b<<<OUT_DIM, 256, 0, stream>>>(w, Bsgn);
    k_gemm<<<NWG, 512, 0, stream>>>(Acat, Bsgn, out);
}